// Round 1
// baseline (743.206 us; speedup 1.0000x reference)
//
#include <hip/hip_runtime.h>
#include <cfloat>
#include <cstdint>

// Model2c: hierarchical sconv network on icosphere-like meshes.
// N5=10242, N4=2562, N3=642, K=7 neighbors, T=16 frames, M=32 base channels.
// All compute fp32 (tolerance = 2% of ref-max; fp32 passes trivially).
// Workspace layout (floats), ~122 MB total — cat7/cat8 are NOT materialized,
// their segments are synthesized in the sconv A-tile loaders.

constexpr int T  = 16;
constexpr int n5 = 10242, n4 = 2562, n3 = 642;
constexpr int K  = 7;

static __device__ __forceinline__ float4 f4max(float4 a, float4 b) {
    return make_float4(fmaxf(a.x, b.x), fmaxf(a.y, b.y), fmaxf(a.z, b.z), fmaxf(a.w, b.w));
}
static __device__ __forceinline__ float4 f4scale(float4 a, float s) {
    return make_float4(a.x * s, a.y * s, a.z * s, a.w * s);
}

// ---------------------------------------------------------------------------
// conv0: c0f = relu(sconv(frame, W0f)), c0a = relu(sconv(aem, W0a)), m0 = cos
// Block 256 = 8 nodes x 32 lanes(d). Cheap layer (Cin=3/1).
// ---------------------------------------------------------------------------
__global__ __launch_bounds__(256) void conv0_kernel(
    const float* __restrict__ frame, const float* __restrict__ aem,
    const float* __restrict__ W0f, const float* __restrict__ b0f,
    const float* __restrict__ W0a, const float* __restrict__ b0a,
    const int* __restrict__ neigh5,
    float* __restrict__ c0f, float* __restrict__ c0a, float* __restrict__ m0)
{
    const int g = threadIdx.x >> 5;       // node within block
    const int d = threadIdx.x & 31;       // output channel
    const int per_t = (n5 + 7) / 8;
    const int t = blockIdx.x / per_t;
    const int n = (blockIdx.x % per_t) * 8 + g;
    if (n >= n5) return;                  // whole 32-lane group exits together

    float accf = b0f[d];
    float acca = b0a[d];
    const int* nb = neigh5 + n * K;
    #pragma unroll
    for (int k = 0; k < K; ++k) {
        const int j = nb[k];
        const float* fr = frame + ((size_t)t * n5 + j) * 3;
        const float av = aem[(size_t)t * n5 + j];
        accf = fmaf(fr[0], W0f[(k * 3 + 0) * 32 + d], accf);
        accf = fmaf(fr[1], W0f[(k * 3 + 1) * 32 + d], accf);
        accf = fmaf(fr[2], W0f[(k * 3 + 2) * 32 + d], accf);
        acca = fmaf(av, W0a[k * 32 + d], acca);
    }
    accf = fmaxf(accf, 0.f);
    acca = fmaxf(acca, 0.f);

    // cosine similarity across the 32 channels of this node group
    float dot = accf * acca, ff = accf * accf, aa = acca * acca;
    #pragma unroll
    for (int m = 1; m < 32; m <<= 1) {
        dot += __shfl_xor(dot, m, 32);
        ff  += __shfl_xor(ff,  m, 32);
        aa  += __shfl_xor(aa,  m, 32);
    }
    const size_t base = ((size_t)t * n5 + n) * 32;
    c0f[base + d] = accf;
    c0a[base + d] = acca;
    if (d == 0) m0[(size_t)t * n5 + n] = dot / fmaxf(sqrtf(ff) * sqrtf(aa), 1e-8f);
}

// ---------------------------------------------------------------------------
// pool: out[t,n,c] = max_k in[t, pidx[n,k], c]   (float4 per thread)
// ---------------------------------------------------------------------------
template<int C>
__global__ __launch_bounds__(256) void pool_kernel(
    const float* __restrict__ in, const int* __restrict__ pidx,
    int Nin, int Nout, float* __restrict__ out)
{
    constexpr int C4 = C / 4;
    const int idx = blockIdx.x * 256 + threadIdx.x;
    if (idx >= T * Nout * C4) return;
    const int c4 = idx % C4;
    const int n  = (idx / C4) % Nout;
    const int t  = idx / (C4 * Nout);
    const int* pp = pidx + n * K;
    float4 mx = make_float4(-FLT_MAX, -FLT_MAX, -FLT_MAX, -FLT_MAX);
    #pragma unroll
    for (int k = 0; k < K; ++k) {
        const float4 v = reinterpret_cast<const float4*>(in + ((size_t)t * Nin + pp[k]) * C)[c4];
        mx = f4max(mx, v);
    }
    reinterpret_cast<float4*>(out + ((size_t)t * Nout + n) * C)[c4] = mx;
}

// ---------------------------------------------------------------------------
// cos: m[t,n] = cos(f[t,n,:], a[t,n,:]) over C channels; one wave per node.
// ---------------------------------------------------------------------------
template<int C>
__global__ __launch_bounds__(256) void cos_kernel(
    const float* __restrict__ f, const float* __restrict__ a, int N,
    float* __restrict__ m)
{
    const int w = threadIdx.x >> 6, lane = threadIdx.x & 63;
    const int idx = blockIdx.x * 4 + w;   // t*N + n
    if (idx >= T * N) return;
    const float* fr = f + (size_t)idx * C;
    const float* ar = a + (size_t)idx * C;
    float dot = 0.f, ff = 0.f, aa = 0.f;
    #pragma unroll
    for (int c = lane; c < C; c += 64) {
        const float x = fr[c], y = ar[c];
        dot = fmaf(x, y, dot);
        ff  = fmaf(x, x, ff);
        aa  = fmaf(y, y, aa);
    }
    #pragma unroll
    for (int msk = 1; msk < 64; msk <<= 1) {
        dot += __shfl_xor(dot, msk);
        ff  += __shfl_xor(ff,  msk);
        aa  += __shfl_xor(aa,  msk);
    }
    if (lane == 0) m[idx] = dot / fmaxf(sqrtf(ff) * sqrtf(aa), 1e-8f);
}

// ---------------------------------------------------------------------------
// sconv A-tile loaders: return 16B of the (virtual) input row for `node`.
// ---------------------------------------------------------------------------
struct PlainLoader {
    const float* x; int N; int C;
    __device__ __forceinline__ float4 row4(int t, int node, int c4) const {
        return reinterpret_cast<const float4*>(x + ((size_t)t * N + node) * C)[c4];
    }
};

// cat7 row = [ c2f[up4]*m2 (128) | c2a[up4]*m2 (128) | c1f*m1 (64) | c1a*m1 (64) ]
struct Cat7Loader {
    const float* c2f; const float* c2a; const float* c1f; const float* c1a;
    const float* m2;  const float* m1;  const int* up4;
    __device__ __forceinline__ float4 row4(int t, int node, int c4) const {
        const int c = c4 * 4;
        if (c < 256) {
            const int j = up4[node];
            const float mm = m2[(size_t)t * n3 + j];
            const float* src = (c < 128) ? c2f : c2a;
            const float4 v = reinterpret_cast<const float4*>(
                src + ((size_t)t * n3 + j) * 128)[(c & 127) >> 2];
            return f4scale(v, mm);
        } else {
            const float mm = m1[(size_t)t * n4 + node];
            const float* src = (c < 320) ? c1f : c1a;
            const float4 v = reinterpret_cast<const float4*>(
                src + ((size_t)t * n4 + node) * 64)[(c & 63) >> 2];
            return f4scale(v, mm);
        }
    }
};

// cat8 row = [ conv7[up5] (64) | c0f*m0 (32) | c0a*m0 (32) ]
struct Cat8Loader {
    const float* conv7; const float* c0f; const float* c0a;
    const float* m0; const int* up5;
    __device__ __forceinline__ float4 row4(int t, int node, int c4) const {
        const int c = c4 * 4;
        if (c < 64) {
            const int j = up5[node];
            return reinterpret_cast<const float4*>(conv7 + ((size_t)t * n4 + j) * 64)[c >> 2];
        }
        const float mm = m0[(size_t)t * n5 + node];
        const float* src = (c < 96) ? c0f : c0a;
        const float4 v = reinterpret_cast<const float4*>(
            src + ((size_t)t * n5 + node) * 32)[((c - 64) & 31) >> 2];
        return f4scale(v, mm);
    }
};

// ---------------------------------------------------------------------------
// sconv GEMM: out[t,n,d] = relu( sum_{k,c} in[t, neigh[n,k], c] * W[k,c,d] + b[d] )
// BM=64 rows x COUT cols per block, BK=32 staged per (k, cin-chunk).
// Thread tile TM=4 x TN=COUT/16 (256 threads = 16 rowgrp x 16 colgrp).
// ---------------------------------------------------------------------------
template<int CIN, int COUT, bool RELU, class Loader>
__global__ __launch_bounds__(256) void sconv_kernel(
    Loader ldr, const int* __restrict__ neigh, int N,
    const float* __restrict__ W, const float* __restrict__ bias,
    float* __restrict__ out)
{
    constexpr int BM = 64, BK = 32, TM = 4, TN = COUT / 16;
    __shared__ float As[BK][BM + 4];       // [c][r], 272B row stride (16B aligned)
    __shared__ float Ws[BK * COUT];        // [c][d]
    __shared__ int   nbs[K][BM];

    const int tiles = (N + BM - 1) / BM;
    const int t   = blockIdx.x / tiles;
    const int n0  = (blockIdx.x % tiles) * BM;
    const int tid = threadIdx.x;

    for (int i = tid; i < K * BM; i += 256) {
        const int r = i / K, k = i - r * K;
        const int n = min(n0 + r, N - 1);
        nbs[k][r] = neigh[n * K + k];
    }

    float acc[TM][TN];
    #pragma unroll
    for (int i = 0; i < TM; ++i)
        #pragma unroll
        for (int j = 0; j < TN; ++j) acc[i][j] = 0.f;

    const int tr = tid >> 4, tc = tid & 15;     // compute mapping
    const int rs = tid >> 2, q  = tid & 3;      // A-stage mapping
    __syncthreads();

    for (int k = 0; k < K; ++k) {
        for (int c0 = 0; c0 < CIN; c0 += BK) {
            // issue global loads before the barrier (overlap with prior compute)
            const int nb = nbs[k][rs];
            const float4 v0 = ldr.row4(t, nb, (c0 >> 2) + q);
            const float4 v1 = ldr.row4(t, nb, (c0 >> 2) + 4 + q);
            const float4* wsrc = reinterpret_cast<const float4*>(W + ((size_t)k * CIN + c0) * COUT);
            float4 wreg[COUT / 32];
            #pragma unroll
            for (int i = 0; i < COUT / 32; ++i) wreg[i] = wsrc[tid + i * 256];

            __syncthreads();   // previous compute done; safe to overwrite LDS
            As[q * 4 + 0][rs] = v0.x;  As[q * 4 + 1][rs] = v0.y;
            As[q * 4 + 2][rs] = v0.z;  As[q * 4 + 3][rs] = v0.w;
            As[16 + q * 4 + 0][rs] = v1.x;  As[16 + q * 4 + 1][rs] = v1.y;
            As[16 + q * 4 + 2][rs] = v1.z;  As[16 + q * 4 + 3][rs] = v1.w;
            float4* wdst = reinterpret_cast<float4*>(Ws);
            #pragma unroll
            for (int i = 0; i < COUT / 32; ++i) wdst[tid + i * 256] = wreg[i];
            __syncthreads();

            #pragma unroll
            for (int c = 0; c < BK; ++c) {
                float a[TM];
                *reinterpret_cast<float4*>(a) =
                    *reinterpret_cast<const float4*>(&As[c][tr * TM]);
                float w[TN];
                if constexpr (TN == 2) {
                    *reinterpret_cast<float2*>(w) =
                        *reinterpret_cast<const float2*>(&Ws[c * COUT + tc * TN]);
                } else {
                    #pragma unroll
                    for (int j4 = 0; j4 < TN / 4; ++j4)
                        reinterpret_cast<float4*>(w)[j4] =
                            reinterpret_cast<const float4*>(&Ws[c * COUT + tc * TN])[j4];
                }
                #pragma unroll
                for (int i = 0; i < TM; ++i)
                    #pragma unroll
                    for (int j = 0; j < TN; ++j)
                        acc[i][j] = fmaf(a[i], w[j], acc[i][j]);
            }
        }
    }

    #pragma unroll
    for (int i = 0; i < TM; ++i) {
        const int n = n0 + tr * TM + i;
        if (n < N) {
            float v[TN];
            #pragma unroll
            for (int j = 0; j < TN; ++j) {
                const float z = acc[i][j] + bias[tc * TN + j];
                v[j] = RELU ? fmaxf(z, 0.f) : z;
            }
            float* orow = out + ((size_t)t * N + n) * COUT + tc * TN;
            if constexpr (TN == 2) {
                *reinterpret_cast<float2*>(orow) = *reinterpret_cast<const float2*>(v);
            } else {
                #pragma unroll
                for (int j4 = 0; j4 < TN / 4; ++j4)
                    reinterpret_cast<float4*>(orow)[j4] =
                        reinterpret_cast<const float4*>(v)[j4];
            }
        }
    }
}

// ---------------------------------------------------------------------------
// conv9: logits[t,n] = sum_{k,c} conv8[t, neigh5[n,k], c] * W9[k,c] + b9
// ---------------------------------------------------------------------------
__global__ __launch_bounds__(256) void conv9_kernel(
    const float* __restrict__ conv8, const int* __restrict__ neigh5,
    const float* __restrict__ W9, const float* __restrict__ b9,
    float* __restrict__ logits)
{
    const int idx = blockIdx.x * 256 + threadIdx.x;   // t*n5 + n
    if (idx >= T * n5) return;
    const int n = idx % n5;
    const int t = idx / n5;
    float acc = b9[0];
    const int* nb = neigh5 + n * K;
    #pragma unroll
    for (int k = 0; k < K; ++k) {
        const float4* row = reinterpret_cast<const float4*>(conv8 + ((size_t)t * n5 + nb[k]) * 32);
        const float4* wk  = reinterpret_cast<const float4*>(W9 + k * 32);
        #pragma unroll
        for (int c4 = 0; c4 < 8; ++c4) {
            const float4 v = row[c4], w = wk[c4];
            acc = fmaf(v.x, w.x, acc);
            acc = fmaf(v.y, w.y, acc);
            acc = fmaf(v.z, w.z, acc);
            acc = fmaf(v.w, w.w, acc);
        }
    }
    logits[idx] = acc;
}

// ---------------------------------------------------------------------------
// softmax over N5 per t (16 rows). One block per row.
// ---------------------------------------------------------------------------
__global__ __launch_bounds__(1024) void softmax_kernel(
    const float* __restrict__ logits, float* __restrict__ out)
{
    const int t = blockIdx.x, tid = threadIdx.x;
    const float* x = logits + (size_t)t * n5;
    float* y = out + (size_t)t * n5;
    __shared__ float redmax[16], redsum[16];

    float mx = -FLT_MAX;
    for (int i = tid; i < n5; i += 1024) mx = fmaxf(mx, x[i]);
    #pragma unroll
    for (int m = 1; m < 64; m <<= 1) mx = fmaxf(mx, __shfl_xor(mx, m));
    if ((tid & 63) == 0) redmax[tid >> 6] = mx;
    __syncthreads();
    mx = redmax[0];
    #pragma unroll
    for (int i = 1; i < 16; ++i) mx = fmaxf(mx, redmax[i]);

    float s = 0.f;
    for (int i = tid; i < n5; i += 1024) s += expf(x[i] - mx);
    #pragma unroll
    for (int m = 1; m < 64; m <<= 1) s += __shfl_xor(s, m);
    if ((tid & 63) == 0) redsum[tid >> 6] = s;
    __syncthreads();
    s = 0.f;
    #pragma unroll
    for (int i = 0; i < 16; ++i) s += redsum[i];

    for (int i = tid; i < n5; i += 1024) y[i] = expf(x[i] - mx) / s;
}

// ---------------------------------------------------------------------------
extern "C" void kernel_launch(void* const* d_in, const int* in_sizes, int n_in,
                              void* d_out, int out_size, void* d_ws, size_t ws_size,
                              hipStream_t stream)
{
    const float* frame = (const float*)d_in[0];
    const float* aem   = (const float*)d_in[1];
    const float* W0f = (const float*)d_in[2];
    const float* b0f = (const float*)d_in[3];
    const float* W0a = (const float*)d_in[4];
    const float* b0a = (const float*)d_in[5];
    const float* W1f = (const float*)d_in[6];
    const float* b1f = (const float*)d_in[7];
    const float* W1a = (const float*)d_in[8];
    const float* b1a = (const float*)d_in[9];
    const float* W2f = (const float*)d_in[10];
    const float* b2f = (const float*)d_in[11];
    const float* W2a = (const float*)d_in[12];
    const float* b2a = (const float*)d_in[13];
    const float* W7  = (const float*)d_in[14];
    const float* b7  = (const float*)d_in[15];
    const float* W8  = (const float*)d_in[16];
    const float* b8  = (const float*)d_in[17];
    const float* W9  = (const float*)d_in[18];
    const float* b9  = (const float*)d_in[19];
    const int* neigh5 = (const int*)d_in[20];
    const int* neigh4 = (const int*)d_in[21];
    const int* neigh3 = (const int*)d_in[22];
    const int* pool5  = (const int*)d_in[23];
    const int* pool4  = (const int*)d_in[24];
    const int* up4    = (const int*)d_in[25];
    const int* up5    = (const int*)d_in[26];
    // d_in[27] = Tlocation (unused by the reference)

    float* ws = (float*)d_ws;
    size_t off = 0;
    auto alloc = [&](size_t count) { float* p = ws + off; off += count; return p; };
    float* c0f = alloc((size_t)T * n5 * 32);
    float* c0a = alloc((size_t)T * n5 * 32);
    float* m0  = alloc((size_t)T * n5);
    float* p0f = alloc((size_t)T * n4 * 32);
    float* p0a = alloc((size_t)T * n4 * 32);
    float* c1f = alloc((size_t)T * n4 * 64);
    float* c1a = alloc((size_t)T * n4 * 64);
    float* m1  = alloc((size_t)T * n4);
    float* p1f = alloc((size_t)T * n3 * 64);
    float* p1a = alloc((size_t)T * n3 * 64);
    float* c2f = alloc((size_t)T * n3 * 128);
    float* c2a = alloc((size_t)T * n3 * 128);
    float* m2  = alloc((size_t)T * n3);
    float* cv7 = alloc((size_t)T * n4 * 64);
    float* cv8 = alloc((size_t)T * n5 * 32);
    float* lgt = alloc((size_t)T * n5);
    // total ~30.5M floats = ~122 MB

    conv0_kernel<<<T * ((n5 + 7) / 8), 256, 0, stream>>>(
        frame, aem, W0f, b0f, W0a, b0a, neigh5, c0f, c0a, m0);

    {
        const int thr = T * n4 * (32 / 4);
        pool_kernel<32><<<(thr + 255) / 256, 256, 0, stream>>>(c0f, pool5, n5, n4, p0f);
        pool_kernel<32><<<(thr + 255) / 256, 256, 0, stream>>>(c0a, pool5, n5, n4, p0a);
    }

    sconv_kernel<32, 64, true><<<T * ((n4 + 63) / 64), 256, 0, stream>>>(
        PlainLoader{p0f, n4, 32}, neigh4, n4, W1f, b1f, c1f);
    sconv_kernel<32, 64, true><<<T * ((n4 + 63) / 64), 256, 0, stream>>>(
        PlainLoader{p0a, n4, 32}, neigh4, n4, W1a, b1a, c1a);
    cos_kernel<64><<<(T * n4 + 3) / 4, 256, 0, stream>>>(c1f, c1a, n4, m1);

    {
        const int thr = T * n3 * (64 / 4);
        pool_kernel<64><<<(thr + 255) / 256, 256, 0, stream>>>(c1f, pool4, n4, n3, p1f);
        pool_kernel<64><<<(thr + 255) / 256, 256, 0, stream>>>(c1a, pool4, n4, n3, p1a);
    }

    sconv_kernel<64, 128, true><<<T * ((n3 + 63) / 64), 256, 0, stream>>>(
        PlainLoader{p1f, n3, 64}, neigh3, n3, W2f, b2f, c2f);
    sconv_kernel<64, 128, true><<<T * ((n3 + 63) / 64), 256, 0, stream>>>(
        PlainLoader{p1a, n3, 64}, neigh3, n3, W2a, b2a, c2a);
    cos_kernel<128><<<(T * n3 + 3) / 4, 256, 0, stream>>>(c2f, c2a, n3, m2);

    sconv_kernel<384, 64, true><<<T * ((n4 + 63) / 64), 256, 0, stream>>>(
        Cat7Loader{c2f, c2a, c1f, c1a, m2, m1, up4}, neigh4, n4, W7, b7, cv7);

    sconv_kernel<128, 32, true><<<T * ((n5 + 63) / 64), 256, 0, stream>>>(
        Cat8Loader{cv7, c0f, c0a, m0, up5}, neigh5, n5, W8, b8, cv8);

    conv9_kernel<<<(T * n5 + 255) / 256, 256, 0, stream>>>(cv8, neigh5, W9, b9, lgt);

    softmax_kernel<<<T, 1024, 0, stream>>>(lgt, (float*)d_out);
}

// Round 2
// 577.550 us; speedup vs baseline: 1.2868x; 1.2868x over previous
//
#include <hip/hip_runtime.h>
#include <cfloat>
#include <cstdint>

// Model2c: hierarchical sconv network.
// Round 2: conv7 (CIN=384) and conv8 (CIN=128) moved to bf16 MFMA
// (mfma_f32_16x16x32_bf16, fp32 accumulate). Everything else fp32.
// Weights for those layers are pre-transposed+converted to bf16 [COUT][K*CIN]
// by a tiny prep kernel; the buffer aliases the `lgt` region (written only
// later by conv9), so workspace use is unchanged vs round 1 (~122 MB).

constexpr int T  = 16;
constexpr int n5 = 10242, n4 = 2562, n3 = 642;
constexpr int K  = 7;

using bf16x8 = __attribute__((ext_vector_type(8))) short;   // 8 bf16
using f32x4  = __attribute__((ext_vector_type(4))) float;

static __device__ __forceinline__ float4 f4max(float4 a, float4 b) {
    return make_float4(fmaxf(a.x, b.x), fmaxf(a.y, b.y), fmaxf(a.z, b.z), fmaxf(a.w, b.w));
}
static __device__ __forceinline__ float4 f4scale(float4 a, float s) {
    return make_float4(a.x * s, a.y * s, a.z * s, a.w * s);
}
// pack two fp32 -> one uint holding 2 bf16 (RNE)
static __device__ __forceinline__ unsigned pack_bf2(float lo, float hi) {
    unsigned a = __float_as_uint(lo), b = __float_as_uint(hi);
    a += 0x7FFF + ((a >> 16) & 1);
    b += 0x7FFF + ((b >> 16) & 1);
    return (a >> 16) | (b & 0xFFFF0000u);
}

// ---------------------------------------------------------------------------
// conv0 (unchanged)
// ---------------------------------------------------------------------------
__global__ __launch_bounds__(256) void conv0_kernel(
    const float* __restrict__ frame, const float* __restrict__ aem,
    const float* __restrict__ W0f, const float* __restrict__ b0f,
    const float* __restrict__ W0a, const float* __restrict__ b0a,
    const int* __restrict__ neigh5,
    float* __restrict__ c0f, float* __restrict__ c0a, float* __restrict__ m0)
{
    const int g = threadIdx.x >> 5;
    const int d = threadIdx.x & 31;
    const int per_t = (n5 + 7) / 8;
    const int t = blockIdx.x / per_t;
    const int n = (blockIdx.x % per_t) * 8 + g;
    if (n >= n5) return;

    float accf = b0f[d];
    float acca = b0a[d];
    const int* nb = neigh5 + n * K;
    #pragma unroll
    for (int k = 0; k < K; ++k) {
        const int j = nb[k];
        const float* fr = frame + ((size_t)t * n5 + j) * 3;
        const float av = aem[(size_t)t * n5 + j];
        accf = fmaf(fr[0], W0f[(k * 3 + 0) * 32 + d], accf);
        accf = fmaf(fr[1], W0f[(k * 3 + 1) * 32 + d], accf);
        accf = fmaf(fr[2], W0f[(k * 3 + 2) * 32 + d], accf);
        acca = fmaf(av, W0a[k * 32 + d], acca);
    }
    accf = fmaxf(accf, 0.f);
    acca = fmaxf(acca, 0.f);

    float dot = accf * acca, ff = accf * accf, aa = acca * acca;
    #pragma unroll
    for (int m = 1; m < 32; m <<= 1) {
        dot += __shfl_xor(dot, m, 32);
        ff  += __shfl_xor(ff,  m, 32);
        aa  += __shfl_xor(aa,  m, 32);
    }
    const size_t base = ((size_t)t * n5 + n) * 32;
    c0f[base + d] = accf;
    c0a[base + d] = acca;
    if (d == 0) m0[(size_t)t * n5 + n] = dot / fmaxf(sqrtf(ff) * sqrtf(aa), 1e-8f);
}

// ---------------------------------------------------------------------------
// pool / cos (unchanged)
// ---------------------------------------------------------------------------
template<int C>
__global__ __launch_bounds__(256) void pool_kernel(
    const float* __restrict__ in, const int* __restrict__ pidx,
    int Nin, int Nout, float* __restrict__ out)
{
    constexpr int C4 = C / 4;
    const int idx = blockIdx.x * 256 + threadIdx.x;
    if (idx >= T * Nout * C4) return;
    const int c4 = idx % C4;
    const int n  = (idx / C4) % Nout;
    const int t  = idx / (C4 * Nout);
    const int* pp = pidx + n * K;
    float4 mx = make_float4(-FLT_MAX, -FLT_MAX, -FLT_MAX, -FLT_MAX);
    #pragma unroll
    for (int k = 0; k < K; ++k) {
        const float4 v = reinterpret_cast<const float4*>(in + ((size_t)t * Nin + pp[k]) * C)[c4];
        mx = f4max(mx, v);
    }
    reinterpret_cast<float4*>(out + ((size_t)t * Nout + n) * C)[c4] = mx;
}

template<int C>
__global__ __launch_bounds__(256) void cos_kernel(
    const float* __restrict__ f, const float* __restrict__ a, int N,
    float* __restrict__ m)
{
    const int w = threadIdx.x >> 6, lane = threadIdx.x & 63;
    const int idx = blockIdx.x * 4 + w;
    if (idx >= T * N) return;
    const float* fr = f + (size_t)idx * C;
    const float* ar = a + (size_t)idx * C;
    float dot = 0.f, ff = 0.f, aa = 0.f;
    #pragma unroll
    for (int c = lane; c < C; c += 64) {
        const float x = fr[c], y = ar[c];
        dot = fmaf(x, y, dot);
        ff  = fmaf(x, x, ff);
        aa  = fmaf(y, y, aa);
    }
    #pragma unroll
    for (int msk = 1; msk < 64; msk <<= 1) {
        dot += __shfl_xor(dot, msk);
        ff  += __shfl_xor(ff,  msk);
        aa  += __shfl_xor(aa,  msk);
    }
    if (lane == 0) m[idx] = dot / fmaxf(sqrtf(ff) * sqrtf(aa), 1e-8f);
}

// ---------------------------------------------------------------------------
// Loaders (virtual A-row synthesis)
// ---------------------------------------------------------------------------
struct PlainLoader {
    const float* x; int N; int C;
    __device__ __forceinline__ float4 row4(int t, int node, int c4) const {
        return reinterpret_cast<const float4*>(x + ((size_t)t * N + node) * C)[c4];
    }
};

struct Cat7Loader {
    const float* c2f; const float* c2a; const float* c1f; const float* c1a;
    const float* m2;  const float* m1;  const int* up4;
    __device__ __forceinline__ float4 row4(int t, int node, int c4) const {
        const int c = c4 * 4;
        if (c < 256) {
            const int j = up4[node];
            const float mm = m2[(size_t)t * n3 + j];
            const float* src = (c < 128) ? c2f : c2a;
            const float4 v = reinterpret_cast<const float4*>(
                src + ((size_t)t * n3 + j) * 128)[(c & 127) >> 2];
            return f4scale(v, mm);
        } else {
            const float mm = m1[(size_t)t * n4 + node];
            const float* src = (c < 320) ? c1f : c1a;
            const float4 v = reinterpret_cast<const float4*>(
                src + ((size_t)t * n4 + node) * 64)[(c & 63) >> 2];
            return f4scale(v, mm);
        }
    }
};

struct Cat8Loader {
    const float* conv7; const float* c0f; const float* c0a;
    const float* m0; const int* up5;
    __device__ __forceinline__ float4 row4(int t, int node, int c4) const {
        const int c = c4 * 4;
        if (c < 64) {
            const int j = up5[node];
            return reinterpret_cast<const float4*>(conv7 + ((size_t)t * n4 + j) * 64)[c >> 2];
        }
        const float mm = m0[(size_t)t * n5 + node];
        const float* src = (c < 96) ? c0f : c0a;
        const float4 v = reinterpret_cast<const float4*>(
            src + ((size_t)t * n5 + node) * 32)[((c - 64) & 31) >> 2];
        return f4scale(v, mm);
    }
};

// ---------------------------------------------------------------------------
// fp32 sconv (kept for conv1 / conv2)
// ---------------------------------------------------------------------------
template<int CIN, int COUT, bool RELU, class Loader>
__global__ __launch_bounds__(256) void sconv_kernel(
    Loader ldr, const int* __restrict__ neigh, int N,
    const float* __restrict__ W, const float* __restrict__ bias,
    float* __restrict__ out)
{
    constexpr int BM = 64, BK = 32, TM = 4, TN = COUT / 16;
    __shared__ float As[BK][BM + 4];
    __shared__ float Ws[BK * COUT];
    __shared__ int   nbs[K][BM];

    const int tiles = (N + BM - 1) / BM;
    const int t   = blockIdx.x / tiles;
    const int n0  = (blockIdx.x % tiles) * BM;
    const int tid = threadIdx.x;

    for (int i = tid; i < K * BM; i += 256) {
        const int r = i / K, k = i - r * K;
        const int n = min(n0 + r, N - 1);
        nbs[k][r] = neigh[n * K + k];
    }

    float acc[TM][TN];
    #pragma unroll
    for (int i = 0; i < TM; ++i)
        #pragma unroll
        for (int j = 0; j < TN; ++j) acc[i][j] = 0.f;

    const int tr = tid >> 4, tc = tid & 15;
    const int rs = tid >> 2, q  = tid & 3;
    __syncthreads();

    for (int k = 0; k < K; ++k) {
        for (int c0 = 0; c0 < CIN; c0 += BK) {
            const int nb = nbs[k][rs];
            const float4 v0 = ldr.row4(t, nb, (c0 >> 2) + q);
            const float4 v1 = ldr.row4(t, nb, (c0 >> 2) + 4 + q);
            const float4* wsrc = reinterpret_cast<const float4*>(W + ((size_t)k * CIN + c0) * COUT);
            float4 wreg[COUT / 32];
            #pragma unroll
            for (int i = 0; i < COUT / 32; ++i) wreg[i] = wsrc[tid + i * 256];

            __syncthreads();
            As[q * 4 + 0][rs] = v0.x;  As[q * 4 + 1][rs] = v0.y;
            As[q * 4 + 2][rs] = v0.z;  As[q * 4 + 3][rs] = v0.w;
            As[16 + q * 4 + 0][rs] = v1.x;  As[16 + q * 4 + 1][rs] = v1.y;
            As[16 + q * 4 + 2][rs] = v1.z;  As[16 + q * 4 + 3][rs] = v1.w;
            float4* wdst = reinterpret_cast<float4*>(Ws);
            #pragma unroll
            for (int i = 0; i < COUT / 32; ++i) wdst[tid + i * 256] = wreg[i];
            __syncthreads();

            #pragma unroll
            for (int c = 0; c < BK; ++c) {
                float a[TM];
                *reinterpret_cast<float4*>(a) =
                    *reinterpret_cast<const float4*>(&As[c][tr * TM]);
                float w[TN];
                if constexpr (TN == 2) {
                    *reinterpret_cast<float2*>(w) =
                        *reinterpret_cast<const float2*>(&Ws[c * COUT + tc * TN]);
                } else {
                    #pragma unroll
                    for (int j4 = 0; j4 < TN / 4; ++j4)
                        reinterpret_cast<float4*>(w)[j4] =
                            reinterpret_cast<const float4*>(&Ws[c * COUT + tc * TN])[j4];
                }
                #pragma unroll
                for (int i = 0; i < TM; ++i)
                    #pragma unroll
                    for (int j = 0; j < TN; ++j)
                        acc[i][j] = fmaf(a[i], w[j], acc[i][j]);
            }
        }
    }

    #pragma unroll
    for (int i = 0; i < TM; ++i) {
        const int n = n0 + tr * TM + i;
        if (n < N) {
            float v[TN];
            #pragma unroll
            for (int j = 0; j < TN; ++j) {
                const float z = acc[i][j] + bias[tc * TN + j];
                v[j] = RELU ? fmaxf(z, 0.f) : z;
            }
            float* orow = out + ((size_t)t * N + n) * COUT + tc * TN;
            if constexpr (TN == 2) {
                *reinterpret_cast<float2*>(orow) = *reinterpret_cast<const float2*>(v);
            } else {
                #pragma unroll
                for (int j4 = 0; j4 < TN / 4; ++j4)
                    reinterpret_cast<float4*>(orow)[j4] =
                        reinterpret_cast<const float4*>(v)[j4];
            }
        }
    }
}

// ---------------------------------------------------------------------------
// weight prep: Wt[d][kc] (bf16) <- W[kc][d] (fp32), kc = k*CIN + c
// ---------------------------------------------------------------------------
__global__ __launch_bounds__(256) void wprep_kernel(
    const float* __restrict__ W, unsigned short* __restrict__ Wt,
    int KC, int Cout)
{
    const int idx = blockIdx.x * 256 + threadIdx.x;
    if (idx >= KC * Cout) return;
    const int d = idx / KC, kc = idx - d * KC;
    unsigned u = __float_as_uint(W[(size_t)kc * Cout + d]);
    u += 0x7FFF + ((u >> 16) & 1);
    Wt[idx] = (unsigned short)(u >> 16);
}

// ---------------------------------------------------------------------------
// bf16 MFMA sconv: out[t,n,d] = relu(b[d] + sum_{k,c} A(t,neigh[n,k],c)*W[k,c,d])
// 4 waves, each a 32x32 output tile (2x2 frags of 16x16, K-step 32).
// BM x COUT block tile, BK=64. A gathered+converted to bf16 in LDS;
// W from pre-converted bf16 Wt[COUT][KC]. LDS rows (64 bf16 = 128B) use the
// XOR swizzle idx ^= (row&7)<<3 (ushort units) so ds_read_b128 is conflict-free.
// ---------------------------------------------------------------------------
template<int CIN, int COUT, int BM, bool RELU, class Loader>
__global__ __launch_bounds__(256) void sconv_mfma_kernel(
    Loader ldr, const int* __restrict__ neigh, int N,
    const unsigned short* __restrict__ Wt, const float* __restrict__ bias,
    float* __restrict__ out)
{
    constexpr int KC     = K * CIN;
    constexpr int NK     = KC / 64;        // K-tiles of 64
    constexpr int CHUNKS = CIN / 64;       // 64-chunks per neighbor
    constexpr int WC     = COUT / 32;      // wave-grid cols
    static_assert(BM * COUT == 4096, "4 waves x 32x32");
    static_assert(CIN % 64 == 0, "BK=64 must divide CIN");

    __shared__ __align__(16) unsigned short As[BM * 64];
    __shared__ __align__(16) unsigned short Ws[COUT * 64];
    __shared__ int nbs[K][BM];

    const int tiles = (N + BM - 1) / BM;
    const int t   = blockIdx.x / tiles;
    const int n0  = (blockIdx.x % tiles) * BM;
    const int tid = threadIdx.x;
    const int lane = tid & 63;
    const int wave = tid >> 6;
    const int wr = wave / WC, wcol = wave % WC;
    const int l15 = lane & 15, lhi = lane >> 4;

    for (int i = tid; i < K * BM; i += 256) {
        const int r = i / K, k = i - r * K;
        nbs[k][r] = neigh[min(n0 + r, N - 1) * K + k];
    }

    f32x4 acc[2][2] = {};

    // staging maps
    const int ar = tid >> 2, aq = tid & 3;         // A: 4 thr/row, 16 bf16 each
    constexpr int WTPR = 256 / COUT;                // W threads per row
    constexpr int WCPT = 64 / WTPR;                 // W cols per thread (16 or 8)
    const int wd = tid / WTPR, wq = tid % WTPR;

    __syncthreads();

    for (int kt = 0; kt < NK; ++kt) {
        const int k  = kt / CHUNKS;
        const int c0 = (kt - k * CHUNKS) * 64;

        // ---- global loads into regs ----
        float4 av[BM / 64][4];
        #pragma unroll
        for (int rb = 0; rb < BM / 64; ++rb) {
            const int row = rb * 64 + ar;
            const int nb = nbs[k][row];
            #pragma unroll
            for (int h = 0; h < 4; ++h)
                av[rb][h] = ldr.row4(t, nb, (c0 >> 2) + aq * 4 + h);
        }
        uint4 wv[WCPT / 8];
        {
            const unsigned short* src = Wt + (size_t)wd * KC + kt * 64 + wq * WCPT;
            #pragma unroll
            for (int h = 0; h < WCPT / 8; ++h)
                wv[h] = reinterpret_cast<const uint4*>(src)[h];
        }

        __syncthreads();    // previous iteration's ds_reads complete

        // ---- convert + LDS writes (swizzled) ----
        #pragma unroll
        for (int rb = 0; rb < BM / 64; ++rb) {
            const int row = rb * 64 + ar;
            unsigned pk[8];
            #pragma unroll
            for (int h = 0; h < 4; ++h) {
                pk[h * 2 + 0] = pack_bf2(av[rb][h].x, av[rb][h].y);
                pk[h * 2 + 1] = pack_bf2(av[rb][h].z, av[rb][h].w);
            }
            const int swz = (row & 7) << 3;
            const int b0 = row * 64 + aq * 16;
            *reinterpret_cast<uint4*>(&As[(b0)     ^ swz]) = make_uint4(pk[0], pk[1], pk[2], pk[3]);
            *reinterpret_cast<uint4*>(&As[(b0 + 8) ^ swz]) = make_uint4(pk[4], pk[5], pk[6], pk[7]);
        }
        {
            const int swz = (wd & 7) << 3;
            #pragma unroll
            for (int h = 0; h < WCPT / 8; ++h)
                *reinterpret_cast<uint4*>(&Ws[(wd * 64 + wq * WCPT + h * 8) ^ swz]) = wv[h];
        }
        __syncthreads();

        // ---- MFMA ----
        #pragma unroll
        for (int kk = 0; kk < 2; ++kk) {
            const int kb = kk * 32 + lhi * 8;
            bf16x8 a[2], b[2];
            #pragma unroll
            for (int m = 0; m < 2; ++m) {
                const int row = wr * 32 + m * 16 + l15;
                a[m] = *reinterpret_cast<const bf16x8*>(&As[(row * 64 + kb) ^ ((row & 7) << 3)]);
            }
            #pragma unroll
            for (int n = 0; n < 2; ++n) {
                const int col = wcol * 32 + n * 16 + l15;
                b[n] = *reinterpret_cast<const bf16x8*>(&Ws[(col * 64 + kb) ^ ((col & 7) << 3)]);
            }
            #pragma unroll
            for (int m = 0; m < 2; ++m)
                #pragma unroll
                for (int n = 0; n < 2; ++n)
                    acc[m][n] = __builtin_amdgcn_mfma_f32_16x16x32_bf16(a[m], b[n], acc[m][n], 0, 0, 0);
        }
    }

    // ---- epilogue: D row=(lane>>4)*4+i, col=lane&15 (m89-verified layout) ----
    #pragma unroll
    for (int n = 0; n < 2; ++n) {
        const int gcol = wcol * 32 + n * 16 + l15;
        const float bv = bias[gcol];
        #pragma unroll
        for (int m = 0; m < 2; ++m) {
            #pragma unroll
            for (int i = 0; i < 4; ++i) {
                const int grow = n0 + wr * 32 + m * 16 + lhi * 4 + i;
                if (grow < N) {
                    float v = acc[m][n][i] + bv;
                    if (RELU) v = fmaxf(v, 0.f);
                    out[((size_t)t * N + grow) * COUT + gcol] = v;
                }
            }
        }
    }
}

// ---------------------------------------------------------------------------
// conv9 + softmax (unchanged)
// ---------------------------------------------------------------------------
__global__ __launch_bounds__(256) void conv9_kernel(
    const float* __restrict__ conv8, const int* __restrict__ neigh5,
    const float* __restrict__ W9, const float* __restrict__ b9,
    float* __restrict__ logits)
{
    const int idx = blockIdx.x * 256 + threadIdx.x;
    if (idx >= T * n5) return;
    const int n = idx % n5;
    const int t = idx / n5;
    float acc = b9[0];
    const int* nb = neigh5 + n * K;
    #pragma unroll
    for (int k = 0; k < K; ++k) {
        const float4* row = reinterpret_cast<const float4*>(conv8 + ((size_t)t * n5 + nb[k]) * 32);
        const float4* wk  = reinterpret_cast<const float4*>(W9 + k * 32);
        #pragma unroll
        for (int c4 = 0; c4 < 8; ++c4) {
            const float4 v = row[c4], w = wk[c4];
            acc = fmaf(v.x, w.x, acc);
            acc = fmaf(v.y, w.y, acc);
            acc = fmaf(v.z, w.z, acc);
            acc = fmaf(v.w, w.w, acc);
        }
    }
    logits[idx] = acc;
}

__global__ __launch_bounds__(1024) void softmax_kernel(
    const float* __restrict__ logits, float* __restrict__ out)
{
    const int t = blockIdx.x, tid = threadIdx.x;
    const float* x = logits + (size_t)t * n5;
    float* y = out + (size_t)t * n5;
    __shared__ float redmax[16], redsum[16];

    float mx = -FLT_MAX;
    for (int i = tid; i < n5; i += 1024) mx = fmaxf(mx, x[i]);
    #pragma unroll
    for (int m = 1; m < 64; m <<= 1) mx = fmaxf(mx, __shfl_xor(mx, m));
    if ((tid & 63) == 0) redmax[tid >> 6] = mx;
    __syncthreads();
    mx = redmax[0];
    #pragma unroll
    for (int i = 1; i < 16; ++i) mx = fmaxf(mx, redmax[i]);

    float s = 0.f;
    for (int i = tid; i < n5; i += 1024) s += expf(x[i] - mx);
    #pragma unroll
    for (int m = 1; m < 64; m <<= 1) s += __shfl_xor(s, m);
    if ((tid & 63) == 0) redsum[tid >> 6] = s;
    __syncthreads();
    s = 0.f;
    #pragma unroll
    for (int i = 0; i < 16; ++i) s += redsum[i];

    for (int i = tid; i < n5; i += 1024) y[i] = expf(x[i] - mx) / s;
}

// ---------------------------------------------------------------------------
extern "C" void kernel_launch(void* const* d_in, const int* in_sizes, int n_in,
                              void* d_out, int out_size, void* d_ws, size_t ws_size,
                              hipStream_t stream)
{
    const float* frame = (const float*)d_in[0];
    const float* aem   = (const float*)d_in[1];
    const float* W0f = (const float*)d_in[2];
    const float* b0f = (const float*)d_in[3];
    const float* W0a = (const float*)d_in[4];
    const float* b0a = (const float*)d_in[5];
    const float* W1f = (const float*)d_in[6];
    const float* b1f = (const float*)d_in[7];
    const float* W1a = (const float*)d_in[8];
    const float* b1a = (const float*)d_in[9];
    const float* W2f = (const float*)d_in[10];
    const float* b2f = (const float*)d_in[11];
    const float* W2a = (const float*)d_in[12];
    const float* b2a = (const float*)d_in[13];
    const float* W7  = (const float*)d_in[14];
    const float* b7  = (const float*)d_in[15];
    const float* W8  = (const float*)d_in[16];
    const float* b8  = (const float*)d_in[17];
    const float* W9  = (const float*)d_in[18];
    const float* b9  = (const float*)d_in[19];
    const int* neigh5 = (const int*)d_in[20];
    const int* neigh4 = (const int*)d_in[21];
    const int* neigh3 = (const int*)d_in[22];
    const int* pool5  = (const int*)d_in[23];
    const int* pool4  = (const int*)d_in[24];
    const int* up4    = (const int*)d_in[25];
    const int* up5    = (const int*)d_in[26];

    float* ws = (float*)d_ws;
    size_t off = 0;
    auto alloc = [&](size_t count) {
        float* p = ws + off; off += (count + 3) & ~(size_t)3; return p;
    };
    float* c0f = alloc((size_t)T * n5 * 32);
    float* c0a = alloc((size_t)T * n5 * 32);
    float* m0  = alloc((size_t)T * n5);
    float* p0f = alloc((size_t)T * n4 * 32);
    float* p0a = alloc((size_t)T * n4 * 32);
    float* c1f = alloc((size_t)T * n4 * 64);
    float* c1a = alloc((size_t)T * n4 * 64);
    float* m1  = alloc((size_t)T * n4);
    float* p1f = alloc((size_t)T * n3 * 64);
    float* p1a = alloc((size_t)T * n3 * 64);
    float* c2f = alloc((size_t)T * n3 * 128);
    float* c2a = alloc((size_t)T * n3 * 128);
    float* m2  = alloc((size_t)T * n3);
    float* cv7 = alloc((size_t)T * n4 * 64);
    float* cv8 = alloc((size_t)T * n5 * 32);
    float* lgt = alloc((size_t)T * n5);   // 655 KB; first ~401 KB aliased by Wt7/Wt8

    // bf16 weight buffers alias lgt (dead until conv9 writes it)
    constexpr int KC7 = K * 384, KC8 = K * 128;
    unsigned short* Wt7 = (unsigned short*)lgt;            // 64*KC7 = 172032 bf16
    unsigned short* Wt8 = Wt7 + (size_t)64 * KC7;          // 32*KC8 =  28672 bf16

    wprep_kernel<<<(64 * KC7 + 255) / 256, 256, 0, stream>>>(W7, Wt7, KC7, 64);
    wprep_kernel<<<(32 * KC8 + 255) / 256, 256, 0, stream>>>(W8, Wt8, KC8, 32);

    conv0_kernel<<<T * ((n5 + 7) / 8), 256, 0, stream>>>(
        frame, aem, W0f, b0f, W0a, b0a, neigh5, c0f, c0a, m0);

    {
        const int thr = T * n4 * (32 / 4);
        pool_kernel<32><<<(thr + 255) / 256, 256, 0, stream>>>(c0f, pool5, n5, n4, p0f);
        pool_kernel<32><<<(thr + 255) / 256, 256, 0, stream>>>(c0a, pool5, n5, n4, p0a);
    }

    sconv_kernel<32, 64, true><<<T * ((n4 + 63) / 64), 256, 0, stream>>>(
        PlainLoader{p0f, n4, 32}, neigh4, n4, W1f, b1f, c1f);
    sconv_kernel<32, 64, true><<<T * ((n4 + 63) / 64), 256, 0, stream>>>(
        PlainLoader{p0a, n4, 32}, neigh4, n4, W1a, b1a, c1a);
    cos_kernel<64><<<(T * n4 + 3) / 4, 256, 0, stream>>>(c1f, c1a, n4, m1);

    {
        const int thr = T * n3 * (64 / 4);
        pool_kernel<64><<<(thr + 255) / 256, 256, 0, stream>>>(c1f, pool4, n4, n3, p1f);
        pool_kernel<64><<<(thr + 255) / 256, 256, 0, stream>>>(c1a, pool4, n4, n3, p1a);
    }

    sconv_kernel<64, 128, true><<<T * ((n3 + 63) / 64), 256, 0, stream>>>(
        PlainLoader{p1f, n3, 64}, neigh3, n3, W2f, b2f, c2f);
    sconv_kernel<64, 128, true><<<T * ((n3 + 63) / 64), 256, 0, stream>>>(
        PlainLoader{p1a, n3, 64}, neigh3, n3, W2a, b2a, c2a);
    cos_kernel<128><<<(T * n3 + 3) / 4, 256, 0, stream>>>(c2f, c2a, n3, m2);

    // conv7: bf16 MFMA, BM=64 x COUT=64
    sconv_mfma_kernel<384, 64, 64, true><<<T * ((n4 + 63) / 64), 256, 0, stream>>>(
        Cat7Loader{c2f, c2a, c1f, c1a, m2, m1, up4}, neigh4, n4, Wt7, b7, cv7);

    // conv8: bf16 MFMA, BM=128 x COUT=32
    sconv_mfma_kernel<128, 32, 128, true><<<T * ((n5 + 127) / 128), 256, 0, stream>>>(
        Cat8Loader{cv7, c0f, c0a, m0, up5}, neigh5, n5, Wt8, b8, cv8);

    conv9_kernel<<<(T * n5 + 255) / 256, 256, 0, stream>>>(cv8, neigh5, W9, b9, lgt);

    softmax_kernel<<<T, 1024, 0, stream>>>(lgt, (float*)d_out);
}

// Round 3
// 323.652 us; speedup vs baseline: 2.2963x; 1.7845x over previous
//
#include <hip/hip_runtime.h>
#include <cfloat>
#include <cstdint>

// Model2c round 3: all heavy activations bf16 (halves gather bytes), attention
// products pre-multiplied into bf16 att buffers (kills the 7x-redundant
// m-multiply in the gather), conv1/conv2/conv7/conv8 all on bf16 MFMA, and an
// XCD-aware blockIdx remap so each XCD's L2 (4 MB) holds exactly 2 t-slices of
// the gather working set (~1-1.7 MB per t). Workspace ~99 MB.

constexpr int T  = 16;
constexpr int n5 = 10242, n4 = 2562, n3 = 642;
constexpr int K  = 7;

using bf16x8 = __attribute__((ext_vector_type(8))) short;
using f32x4  = __attribute__((ext_vector_type(4))) float;

static __device__ __forceinline__ float bf2f(unsigned short u) {
    return __uint_as_float((unsigned)u << 16);
}
static __device__ __forceinline__ unsigned short f2bf(float x) {
    unsigned u = __float_as_uint(x);
    u += 0x7FFF + ((u >> 16) & 1);           // RNE; exact-bf16 inputs unchanged
    return (unsigned short)(u >> 16);
}

// ---------------------------------------------------------------------------
// conv0: c0f/c0a (bf16) + fused cos -> att0 = bf16[c0f*m | c0a*m] (64 ch)
// ---------------------------------------------------------------------------
__global__ __launch_bounds__(256) void conv0_kernel(
    const float* __restrict__ frame, const float* __restrict__ aem,
    const float* __restrict__ W0f, const float* __restrict__ b0f,
    const float* __restrict__ W0a, const float* __restrict__ b0a,
    const int* __restrict__ neigh5,
    unsigned short* __restrict__ c0f, unsigned short* __restrict__ c0a,
    unsigned short* __restrict__ att0)
{
    const int g = threadIdx.x >> 5;
    const int d = threadIdx.x & 31;
    const int per_t = (n5 + 7) / 8;
    const int t = blockIdx.x / per_t;
    const int n = (blockIdx.x % per_t) * 8 + g;
    if (n >= n5) return;

    float accf = b0f[d];
    float acca = b0a[d];
    const int* nb = neigh5 + n * K;
    #pragma unroll
    for (int k = 0; k < K; ++k) {
        const int j = nb[k];
        const float* fr = frame + ((size_t)t * n5 + j) * 3;
        const float av = aem[(size_t)t * n5 + j];
        accf = fmaf(fr[0], W0f[(k * 3 + 0) * 32 + d], accf);
        accf = fmaf(fr[1], W0f[(k * 3 + 1) * 32 + d], accf);
        accf = fmaf(fr[2], W0f[(k * 3 + 2) * 32 + d], accf);
        acca = fmaf(av, W0a[k * 32 + d], acca);
    }
    accf = fmaxf(accf, 0.f);
    acca = fmaxf(acca, 0.f);

    float dot = accf * acca, ff = accf * accf, aa = acca * acca;
    #pragma unroll
    for (int m = 1; m < 32; m <<= 1) {
        dot += __shfl_xor(dot, m, 32);
        ff  += __shfl_xor(ff,  m, 32);
        aa  += __shfl_xor(aa,  m, 32);
    }
    const float mm = dot / fmaxf(sqrtf(ff) * sqrtf(aa), 1e-8f);
    const size_t base = ((size_t)t * n5 + n) * 32;
    c0f[base + d] = f2bf(accf);
    c0a[base + d] = f2bf(acca);
    const size_t abase = ((size_t)t * n5 + n) * 64;
    att0[abase + d]      = f2bf(accf * mm);
    att0[abase + 32 + d] = f2bf(acca * mm);
}

// ---------------------------------------------------------------------------
// pool (bf16 -> bf16), ushort8 per thread
// ---------------------------------------------------------------------------
template<int C>
__global__ __launch_bounds__(256) void pool_kernel(
    const unsigned short* __restrict__ in, const int* __restrict__ pidx,
    int Nin, int Nout, unsigned short* __restrict__ out)
{
    constexpr int C8 = C / 8;
    const int idx = blockIdx.x * 256 + threadIdx.x;
    if (idx >= T * Nout * C8) return;
    const int c8 = idx % C8;
    const int n  = (idx / C8) % Nout;
    const int t  = idx / (C8 * Nout);
    const int* pp = pidx + n * K;
    float m[8];
    #pragma unroll
    for (int j = 0; j < 8; ++j) m[j] = -FLT_MAX;
    #pragma unroll
    for (int k = 0; k < K; ++k) {
        const uint4 v = reinterpret_cast<const uint4*>(in)[((size_t)t * Nin + pp[k]) * C8 + c8];
        const unsigned short* s = reinterpret_cast<const unsigned short*>(&v);
        #pragma unroll
        for (int j = 0; j < 8; ++j) m[j] = fmaxf(m[j], bf2f(s[j]));
    }
    unsigned short o[8];
    #pragma unroll
    for (int j = 0; j < 8; ++j) o[j] = f2bf(m[j]);
    reinterpret_cast<uint4*>(out)[((size_t)t * Nout + n) * C8 + c8] =
        *reinterpret_cast<const uint4*>(o);
}

// ---------------------------------------------------------------------------
// cosatt: m = cos(f,a) over C ch; att row (2C ch) = bf16[f*m | a*m]
// ---------------------------------------------------------------------------
template<int C, int NN>
__global__ __launch_bounds__(256) void cosatt_kernel(
    const unsigned short* __restrict__ f, const unsigned short* __restrict__ a,
    unsigned short* __restrict__ att)
{
    constexpr int CPL = C / 64;
    const int w = threadIdx.x >> 6, lane = threadIdx.x & 63;
    const int idx = blockIdx.x * 4 + w;
    if (idx >= T * NN) return;
    const unsigned short* fr = f + (size_t)idx * C;
    const unsigned short* ar = a + (size_t)idx * C;
    float xs[CPL], ys[CPL];
    float dot = 0.f, ff = 0.f, aa = 0.f;
    #pragma unroll
    for (int i = 0; i < CPL; ++i) {
        const float x = bf2f(fr[lane + i * 64]);
        const float y = bf2f(ar[lane + i * 64]);
        xs[i] = x; ys[i] = y;
        dot = fmaf(x, y, dot);
        ff  = fmaf(x, x, ff);
        aa  = fmaf(y, y, aa);
    }
    #pragma unroll
    for (int msk = 1; msk < 64; msk <<= 1) {
        dot += __shfl_xor(dot, msk);
        ff  += __shfl_xor(ff,  msk);
        aa  += __shfl_xor(aa,  msk);
    }
    const float m = dot / fmaxf(sqrtf(ff) * sqrtf(aa), 1e-8f);
    unsigned short* orow = att + (size_t)idx * 2 * C;
    #pragma unroll
    for (int i = 0; i < CPL; ++i) {
        orow[lane + i * 64]     = f2bf(xs[i] * m);
        orow[C + lane + i * 64] = f2bf(ys[i] * m);
    }
}

// ---------------------------------------------------------------------------
// bf16 A-row loaders: return one 16B chunk (8 ch) of the virtual input row
// ---------------------------------------------------------------------------
struct PlainB16 {
    const unsigned short* x; int N; int C8;
    __device__ __forceinline__ uint4 row8(int t, int node, int c8) const {
        return reinterpret_cast<const uint4*>(x)[((size_t)t * N + node) * C8 + c8];
    }
};

// cat7 row (384 ch, 48 chunks) = [ att2[up4[node]] (256) | att1[node] (128) ]
struct Cat7B16 {
    const unsigned short* att2; const unsigned short* att1; const int* up4;
    __device__ __forceinline__ uint4 row8(int t, int node, int c8) const {
        if (c8 < 32)
            return reinterpret_cast<const uint4*>(att2)[((size_t)t * n3 + up4[node]) * 32 + c8];
        return reinterpret_cast<const uint4*>(att1)[((size_t)t * n4 + node) * 16 + (c8 - 32)];
    }
};

// cat8 row (128 ch, 16 chunks) = [ cv7[up5[node]] (64) | att0[node] (64) ]
struct Cat8B16 {
    const unsigned short* cv7; const unsigned short* att0; const int* up5;
    __device__ __forceinline__ uint4 row8(int t, int node, int c8) const {
        if (c8 < 8)
            return reinterpret_cast<const uint4*>(cv7)[((size_t)t * n4 + up5[node]) * 8 + c8];
        return reinterpret_cast<const uint4*>(att0)[((size_t)t * n5 + node) * 8 + (c8 - 8)];
    }
};

// ---------------------------------------------------------------------------
// weight prep (all layers in one launch): Wt[d][kc] bf16 <- W[kc][d] fp32
// ---------------------------------------------------------------------------
__global__ __launch_bounds__(256) void wprep_all_kernel(
    const float* __restrict__ W1f, const float* __restrict__ W1a,
    const float* __restrict__ W2f, const float* __restrict__ W2a,
    const float* __restrict__ W7,  const float* __restrict__ W8,
    unsigned short* __restrict__ Wt1f, unsigned short* __restrict__ Wt1a,
    unsigned short* __restrict__ Wt2f, unsigned short* __restrict__ Wt2a,
    unsigned short* __restrict__ Wt7,  unsigned short* __restrict__ Wt8)
{
    int idx = blockIdx.x * 256 + threadIdx.x;
    const float* W; unsigned short* Wt; int KCv, CO;
    if (idx < 14336)       { W = W1f; Wt = Wt1f; KCv = 224;  CO = 64;  }
    else if (idx < 28672)  { idx -= 14336;  W = W1a; Wt = Wt1a; KCv = 224;  CO = 64;  }
    else if (idx < 86016)  { idx -= 28672;  W = W2f; Wt = Wt2f; KCv = 448;  CO = 128; }
    else if (idx < 143360) { idx -= 86016;  W = W2a; Wt = Wt2a; KCv = 448;  CO = 128; }
    else if (idx < 315392) { idx -= 143360; W = W7;  Wt = Wt7;  KCv = 2688; CO = 64;  }
    else                   { idx -= 315392; W = W8;  Wt = Wt8;  KCv = 896;  CO = 32;  }
    const int d = idx / KCv, kc = idx - d * KCv;
    Wt[idx] = f2bf(W[(size_t)kc * CO + d]);
}

// ---------------------------------------------------------------------------
// bf16 MFMA sconv. 4 waves x 32x32 output tiles; BM*COUT = 4096; BK in {32,64}.
// A gathered via Loader (bf16, 16B chunks); W from Wt[COUT][K*CIN] bf16.
// LDS XOR swizzle on 16B slots -> ds_read_b128 conflict-light.
// blockIdx remap: XCD x (= blockIdx%8) owns t in {2x, 2x+1} for L2 locality.
// ---------------------------------------------------------------------------
template<int CIN, int COUT, int BM, int BK, class Loader>
__global__ __launch_bounds__(256) void sconv_mfma_kernel(
    Loader ldr, const int* __restrict__ neigh, int N, int tiles,
    const unsigned short* __restrict__ Wt, const float* __restrict__ bias,
    unsigned short* __restrict__ out)
{
    constexpr int KC = K * CIN, CHUNKS = CIN / BK, NK = K * CHUNKS;
    constexpr int WC = COUT / 32 <= 4 ? COUT / 32 : 4;   // 1,2,4
    constexpr int U4R = BK / 8;                          // 16B chunks per row
    constexpr int VPTA = BM * U4R / 256;
    constexpr int VPTW = COUT * U4R / 256;
    static_assert(BM * COUT == 4096 && CIN % BK == 0 && VPTA >= 1 && VPTW >= 1);

    __shared__ __align__(16) unsigned short As[BM * BK];
    __shared__ __align__(16) unsigned short Ws[COUT * BK];
    __shared__ int nbs[K][BM];

    // grid = 16*tiles (always %8==0). xcd = blockIdx%8 under round-robin
    // dispatch; give it t = 2*xcd + (j>=tiles). Bijective.
    const int l = blockIdx.x;
    const int j = l >> 3;
    const int hi = (j >= tiles) ? 1 : 0;
    const int t  = 2 * (l & 7) + hi;
    const int n0 = (j - hi * tiles) * BM;

    const int tid  = threadIdx.x;
    const int lane = tid & 63, wave = tid >> 6;
    const int wr = wave / WC, wcol = wave % WC;
    const int l15 = lane & 15, lhi = lane >> 4;

    for (int i = tid; i < K * BM; i += 256) {
        const int r = i / K, k = i - r * K;
        nbs[k][r] = neigh[min(n0 + r, N - 1) * K + k];
    }

    f32x4 acc[2][2] = {};
    __syncthreads();

    for (int kt = 0; kt < NK; ++kt) {
        const int k   = kt / CHUNKS;
        const int cb8 = (kt - k * CHUNKS) * U4R;

        uint4 av[VPTA];
        #pragma unroll
        for (int v = 0; v < VPTA; ++v) {
            const int g = tid + v * 256, row = g / U4R, c8 = g % U4R;
            av[v] = ldr.row8(t, nbs[k][row], cb8 + c8);
        }
        uint4 wv[VPTW];
        #pragma unroll
        for (int v = 0; v < VPTW; ++v) {
            const int g = tid + v * 256, d = g / U4R, c8 = g % U4R;
            wv[v] = *reinterpret_cast<const uint4*>(Wt + (size_t)d * KC + kt * BK + c8 * 8);
        }

        __syncthreads();   // prior iteration's ds_reads done
        #pragma unroll
        for (int v = 0; v < VPTA; ++v) {
            const int g = tid + v * 256, row = g / U4R, c8 = g % U4R;
            *reinterpret_cast<uint4*>(&As[(row * BK + c8 * 8) ^ ((row & (U4R - 1)) << 3)]) = av[v];
        }
        #pragma unroll
        for (int v = 0; v < VPTW; ++v) {
            const int g = tid + v * 256, d = g / U4R, c8 = g % U4R;
            *reinterpret_cast<uint4*>(&Ws[(d * BK + c8 * 8) ^ ((d & (U4R - 1)) << 3)]) = wv[v];
        }
        __syncthreads();

        #pragma unroll
        for (int kk = 0; kk < BK / 32; ++kk) {
            const int kb = kk * 32 + lhi * 8;
            bf16x8 a[2], b[2];
            #pragma unroll
            for (int m = 0; m < 2; ++m) {
                const int row = wr * 32 + m * 16 + l15;
                a[m] = *reinterpret_cast<const bf16x8*>(
                    &As[(row * BK + kb) ^ ((row & (U4R - 1)) << 3)]);
            }
            #pragma unroll
            for (int n = 0; n < 2; ++n) {
                const int col = wcol * 32 + n * 16 + l15;
                b[n] = *reinterpret_cast<const bf16x8*>(
                    &Ws[(col * BK + kb) ^ ((col & (U4R - 1)) << 3)]);
            }
            #pragma unroll
            for (int m = 0; m < 2; ++m)
                #pragma unroll
                for (int n = 0; n < 2; ++n)
                    acc[m][n] = __builtin_amdgcn_mfma_f32_16x16x32_bf16(a[m], b[n], acc[m][n], 0, 0, 0);
        }
    }

    // epilogue: D col=lane&15, row=(lane>>4)*4+i; relu; bf16 out
    #pragma unroll
    for (int n = 0; n < 2; ++n) {
        const int gcol = wcol * 32 + n * 16 + l15;
        const float bv = bias[gcol];
        #pragma unroll
        for (int m = 0; m < 2; ++m) {
            #pragma unroll
            for (int i = 0; i < 4; ++i) {
                const int grow = n0 + wr * 32 + m * 16 + lhi * 4 + i;
                if (grow < N)
                    out[((size_t)t * N + grow) * COUT + gcol] =
                        f2bf(fmaxf(acc[m][n][i] + bv, 0.f));
            }
        }
    }
}

// ---------------------------------------------------------------------------
// conv9: logits fp32 from bf16 cv8
// ---------------------------------------------------------------------------
__global__ __launch_bounds__(256) void conv9_kernel(
    const unsigned short* __restrict__ cv8, const int* __restrict__ neigh5,
    const float* __restrict__ W9, const float* __restrict__ b9,
    float* __restrict__ logits)
{
    const int idx = blockIdx.x * 256 + threadIdx.x;
    if (idx >= T * n5) return;
    const int n = idx % n5;
    const int t = idx / n5;
    float acc = b9[0];
    const int* nb = neigh5 + n * K;
    #pragma unroll
    for (int k = 0; k < K; ++k) {
        const uint4* row = reinterpret_cast<const uint4*>(cv8 + ((size_t)t * n5 + nb[k]) * 32);
        const float* wk = W9 + k * 32;
        #pragma unroll
        for (int c4 = 0; c4 < 4; ++c4) {
            const uint4 v = row[c4];
            const unsigned short* s = reinterpret_cast<const unsigned short*>(&v);
            #pragma unroll
            for (int jj = 0; jj < 8; ++jj)
                acc = fmaf(bf2f(s[jj]), wk[c4 * 8 + jj], acc);
        }
    }
    logits[idx] = acc;
}

// ---------------------------------------------------------------------------
// softmax (unchanged)
// ---------------------------------------------------------------------------
__global__ __launch_bounds__(1024) void softmax_kernel(
    const float* __restrict__ logits, float* __restrict__ out)
{
    const int t = blockIdx.x, tid = threadIdx.x;
    const float* x = logits + (size_t)t * n5;
    float* y = out + (size_t)t * n5;
    __shared__ float redmax[16], redsum[16];

    float mx = -FLT_MAX;
    for (int i = tid; i < n5; i += 1024) mx = fmaxf(mx, x[i]);
    #pragma unroll
    for (int m = 1; m < 64; m <<= 1) mx = fmaxf(mx, __shfl_xor(mx, m));
    if ((tid & 63) == 0) redmax[tid >> 6] = mx;
    __syncthreads();
    mx = redmax[0];
    #pragma unroll
    for (int i = 1; i < 16; ++i) mx = fmaxf(mx, redmax[i]);

    float s = 0.f;
    for (int i = tid; i < n5; i += 1024) s += expf(x[i] - mx);
    #pragma unroll
    for (int m = 1; m < 64; m <<= 1) s += __shfl_xor(s, m);
    if ((tid & 63) == 0) redsum[tid >> 6] = s;
    __syncthreads();
    s = 0.f;
    #pragma unroll
    for (int i = 0; i < 16; ++i) s += redsum[i];

    for (int i = tid; i < n5; i += 1024) y[i] = expf(x[i] - mx) / s;
}

// ---------------------------------------------------------------------------
extern "C" void kernel_launch(void* const* d_in, const int* in_sizes, int n_in,
                              void* d_out, int out_size, void* d_ws, size_t ws_size,
                              hipStream_t stream)
{
    const float* frame = (const float*)d_in[0];
    const float* aem   = (const float*)d_in[1];
    const float* W0f = (const float*)d_in[2];
    const float* b0f = (const float*)d_in[3];
    const float* W0a = (const float*)d_in[4];
    const float* b0a = (const float*)d_in[5];
    const float* W1f = (const float*)d_in[6];
    const float* b1f = (const float*)d_in[7];
    const float* W1a = (const float*)d_in[8];
    const float* b1a = (const float*)d_in[9];
    const float* W2f = (const float*)d_in[10];
    const float* b2f = (const float*)d_in[11];
    const float* W2a = (const float*)d_in[12];
    const float* b2a = (const float*)d_in[13];
    const float* W7  = (const float*)d_in[14];
    const float* b7  = (const float*)d_in[15];
    const float* W8  = (const float*)d_in[16];
    const float* b8  = (const float*)d_in[17];
    const float* W9  = (const float*)d_in[18];
    const float* b9  = (const float*)d_in[19];
    const int* neigh5 = (const int*)d_in[20];
    const int* neigh4 = (const int*)d_in[21];
    const int* neigh3 = (const int*)d_in[22];
    const int* pool5  = (const int*)d_in[23];
    const int* pool4  = (const int*)d_in[24];
    const int* up4    = (const int*)d_in[25];
    const int* up5    = (const int*)d_in[26];

    unsigned short* wsu = (unsigned short*)d_ws;
    size_t off = 0;
    auto ua = [&](size_t n) {
        unsigned short* p = wsu + off; off += (n + 7) & ~(size_t)7; return p;
    };
    unsigned short* c0f  = ua((size_t)T * n5 * 32);
    unsigned short* c0a  = ua((size_t)T * n5 * 32);
    unsigned short* att0 = ua((size_t)T * n5 * 64);
    unsigned short* p0f  = ua((size_t)T * n4 * 32);
    unsigned short* p0a  = ua((size_t)T * n4 * 32);
    unsigned short* c1f  = ua((size_t)T * n4 * 64);
    unsigned short* c1a  = ua((size_t)T * n4 * 64);
    unsigned short* att1 = ua((size_t)T * n4 * 128);
    unsigned short* p1f  = ua((size_t)T * n3 * 64);
    unsigned short* p1a  = ua((size_t)T * n3 * 64);
    unsigned short* c2f  = ua((size_t)T * n3 * 128);
    unsigned short* c2a  = ua((size_t)T * n3 * 128);
    unsigned short* att2 = ua((size_t)T * n3 * 256);
    unsigned short* cv7  = ua((size_t)T * n4 * 64);
    unsigned short* cv8  = ua((size_t)T * n5 * 32);
    unsigned short* Wt1f = ua((size_t)64 * 224);
    unsigned short* Wt1a = ua((size_t)64 * 224);
    unsigned short* Wt2f = ua((size_t)128 * 448);
    unsigned short* Wt2a = ua((size_t)128 * 448);
    unsigned short* Wt7  = ua((size_t)64 * 2688);
    unsigned short* Wt8  = ua((size_t)32 * 896);
    float* lgt = (float*)(wsu + off);   // T*n5 fp32; total ws ~99 MB

    wprep_all_kernel<<<1344, 256, 0, stream>>>(
        W1f, W1a, W2f, W2a, W7, W8, Wt1f, Wt1a, Wt2f, Wt2a, Wt7, Wt8);

    conv0_kernel<<<T * ((n5 + 7) / 8), 256, 0, stream>>>(
        frame, aem, W0f, b0f, W0a, b0a, neigh5, c0f, c0a, att0);

    {
        const int thr = T * n4 * (32 / 8);
        pool_kernel<32><<<(thr + 255) / 256, 256, 0, stream>>>(c0f, pool5, n5, n4, p0f);
        pool_kernel<32><<<(thr + 255) / 256, 256, 0, stream>>>(c0a, pool5, n5, n4, p0a);
    }

    constexpr int tiles1 = (n4 + 63) / 64;    // 41
    sconv_mfma_kernel<32, 64, 64, 32><<<T * tiles1, 256, 0, stream>>>(
        PlainB16{p0f, n4, 4}, neigh4, n4, tiles1, Wt1f, b1f, c1f);
    sconv_mfma_kernel<32, 64, 64, 32><<<T * tiles1, 256, 0, stream>>>(
        PlainB16{p0a, n4, 4}, neigh4, n4, tiles1, Wt1a, b1a, c1a);
    cosatt_kernel<64, n4><<<(T * n4 + 3) / 4, 256, 0, stream>>>(c1f, c1a, att1);

    {
        const int thr = T * n3 * (64 / 8);
        pool_kernel<64><<<(thr + 255) / 256, 256, 0, stream>>>(c1f, pool4, n4, n3, p1f);
        pool_kernel<64><<<(thr + 255) / 256, 256, 0, stream>>>(c1a, pool4, n4, n3, p1a);
    }

    constexpr int tiles2 = (n3 + 31) / 32;    // 21
    sconv_mfma_kernel<64, 128, 32, 64><<<T * tiles2, 256, 0, stream>>>(
        PlainB16{p1f, n3, 8}, neigh3, n3, tiles2, Wt2f, b2f, c2f);
    sconv_mfma_kernel<64, 128, 32, 64><<<T * tiles2, 256, 0, stream>>>(
        PlainB16{p1a, n3, 8}, neigh3, n3, tiles2, Wt2a, b2a, c2a);
    cosatt_kernel<128, n3><<<(T * n3 + 3) / 4, 256, 0, stream>>>(c2f, c2a, att2);

    constexpr int tiles7 = (n4 + 63) / 64;    // 41
    sconv_mfma_kernel<384, 64, 64, 64><<<T * tiles7, 256, 0, stream>>>(
        Cat7B16{att2, att1, up4}, neigh4, n4, tiles7, Wt7, b7, cv7);

    constexpr int tiles8 = (n5 + 127) / 128;  // 81
    sconv_mfma_kernel<128, 32, 128, 64><<<T * tiles8, 256, 0, stream>>>(
        Cat8B16{cv7, att0, up5}, neigh5, n5, tiles8, Wt8, b8, cv8);

    conv9_kernel<<<(T * n5 + 255) / 256, 256, 0, stream>>>(cv8, neigh5, W9, b9, lgt);

    softmax_kernel<<<T, 1024, 0, stream>>>(lgt, (float*)d_out);
}